// Round 4
// baseline (293.437 us; speedup 1.0000x reference)
//
#include <hip/hip_runtime.h>

#define N_NODES 10000
#define N_EDGES 320000
#define DIM_IN  512
#define DIM_HID 128
#define HC      256   // HEADS*GC
#define NEG_SLOPE 0.2f

// ---------------------------------------------------------------------------
// Software-pipelined, double-buffered fp32 GEMM.
// C[M,N] = act(A[M,K] @ B[K,N] + bias). BM=BN=64, 256 threads, 4x4 micro.
// Pipeline: prefetch tile k+1 into registers while computing tile k from
// LDS; store regs -> alternate LDS buffer; ONE barrier per K-iter. This
// hides the ~500-900cy global-load latency that made the naive loop 18%
// VALUBusy (R3 profile).
// A tile transposed [BK][BM+4] -> float4 LDS reads (store is 4-way
// conflicted at BK=32; accepted, store phase << compute phase).
// ATT: fused attention-score epilogue (one head per block since BN==64).
// ---------------------------------------------------------------------------
template<int BK, bool RELU, bool BIAS, bool ATT>
__global__ __launch_bounds__(256) void gemm_kernel(
    const float* __restrict__ A, const float* __restrict__ B,
    const float* __restrict__ bias, float* __restrict__ C,
    int M, int N, int K,
    const float* __restrict__ att_src, const float* __restrict__ att_dst,
    float* __restrict__ a_src, float* __restrict__ a_dst) {
  constexpr int BM = 64, BN = 64;
  constexpr int NAV = (BM * BK) / 1024;   // float4 A-loads per thread
  constexpr int NBV = (BK * BN) / 1024;   // float4 B-loads per thread
  constexpr int TPR_A = BK / 4;           // threads per A row
  constexpr int ARPP  = 256 / TPR_A;      // A rows per pass
  __shared__ float Ast[2][BK][BM + 4];
  __shared__ float Bs[2][BK][BN];
  const int t  = threadIdx.x;
  const int tx = t & 15, ty = t >> 4;
  const int m0 = blockIdx.x * BM, n0 = blockIdx.y * BN;
  const int arow0 = t / TPR_A;            // A loader row within tile
  const int acol  = (t % TPR_A) * 4;      // A loader k-offset
  const int brow0 = t >> 4;               // B loader k-row
  const int bcol  = (t & 15) * 4;         // B loader col-offset

  float4 avr[NAV], bvr[NBV];
  float acc[4][4] = {};

  auto load_tile = [&](int k0) {
#pragma unroll
    for (int v = 0; v < NAV; ++v) {
      const int grow = m0 + arow0 + v * ARPP;
      avr[v] = (grow < M)
          ? *(const float4*)(A + (size_t)grow * K + k0 + acol)
          : make_float4(0.f, 0.f, 0.f, 0.f);
    }
#pragma unroll
    for (int v = 0; v < NBV; ++v)
      bvr[v] = *(const float4*)(B + (size_t)(k0 + brow0 + v * 16) * N + n0 + bcol);
  };
  auto store_tile = [&](int buf) {
#pragma unroll
    for (int v = 0; v < NAV; ++v) {
      const int r = arow0 + v * ARPP;
      Ast[buf][acol + 0][r] = avr[v].x;
      Ast[buf][acol + 1][r] = avr[v].y;
      Ast[buf][acol + 2][r] = avr[v].z;
      Ast[buf][acol + 3][r] = avr[v].w;
    }
#pragma unroll
    for (int v = 0; v < NBV; ++v)
      *(float4*)&Bs[buf][brow0 + v * 16][bcol] = bvr[v];
  };

  const int nt = K / BK;
  load_tile(0);
  store_tile(0);
  __syncthreads();

  for (int kt = 0; kt < nt; ++kt) {
    const int buf = kt & 1;
    if (kt + 1 < nt) load_tile((kt + 1) * BK);   // prefetch (hidden by compute)
#pragma unroll
    for (int kk = 0; kk < BK; ++kk) {
      const float4 a = *(const float4*)&Ast[buf][kk][ty * 4];
      const float4 b = *(const float4*)&Bs[buf][kk][tx * 4];
      const float as[4] = {a.x, a.y, a.z, a.w};
      const float bs[4] = {b.x, b.y, b.z, b.w};
#pragma unroll
      for (int i = 0; i < 4; ++i)
#pragma unroll
        for (int j = 0; j < 4; ++j) acc[i][j] = fmaf(as[i], bs[j], acc[i][j]);
    }
    if (kt + 1 < nt) {
      store_tile(buf ^ 1);
      __syncthreads();
    }
  }

  float4 bvv = make_float4(0.f, 0.f, 0.f, 0.f);
  if (BIAS) bvv = *(const float4*)(bias + n0 + tx * 4);
#pragma unroll
  for (int i = 0; i < 4; ++i) {
    const int row = m0 + ty * 4 + i;
    if (row < M) {
      float4 v;
      v.x = acc[i][0] + bvv.x; v.y = acc[i][1] + bvv.y;
      v.z = acc[i][2] + bvv.z; v.w = acc[i][3] + bvv.w;
      if (RELU) {
        v.x = fmaxf(v.x, 0.f); v.y = fmaxf(v.y, 0.f);
        v.z = fmaxf(v.z, 0.f); v.w = fmaxf(v.w, 0.f);
      }
      *(float4*)(C + (size_t)row * N + n0 + tx * 4) = v;
    }
  }

  if (ATT) {
    const int hh = n0 >> 6;   // one head per 64-col block
#pragma unroll
    for (int i = 0; i < 4; ++i) {
      float ps = 0.f, pd = 0.f;
#pragma unroll
      for (int j = 0; j < 4; ++j) {
        const int c = tx * 4 + j;
        ps = fmaf(acc[i][j], att_src[hh * 64 + c], ps);
        pd = fmaf(acc[i][j], att_dst[hh * 64 + c], pd);
      }
#pragma unroll
      for (int off = 8; off > 0; off >>= 1) {
        ps += __shfl_down(ps, off, 16);
        pd += __shfl_down(pd, off, 16);
      }
      if (tx == 0) {
        const int row = m0 + ty * 4 + i;
        if (row < M) {
          a_src[row * 4 + hh] = ps;
          a_dst[row * 4 + hh] = pd;
        }
      }
    }
  }
}

// bfuse[c] = sum_k b2[k] * Wg[k,c]
__global__ __launch_bounds__(256) void bias_fuse_kernel(
    const float* __restrict__ b2, const float* __restrict__ Wg,
    float* __restrict__ bfuse) {
  const int c = threadIdx.x;
  float acc = 0.f;
  for (int k = 0; k < DIM_HID; ++k) acc = fmaf(b2[k], Wg[k * HC + c], acc);
  bfuse[c] = acc;
}

// ---------------------------------------------------------------------------
// CSR build: histogram of dst (E real edges + N self loops)
// ---------------------------------------------------------------------------
__global__ __launch_bounds__(256) void hist_kernel(
    const int* __restrict__ dst_arr, int* __restrict__ count) {
  const int id = blockIdx.x * 256 + threadIdx.x;
  if (id < N_EDGES)                 atomicAdd(&count[dst_arr[id]], 1);
  else if (id < N_EDGES + N_NODES)  atomicAdd(&count[id - N_EDGES], 1);
}

// Work-efficient single-block scan: 256 threads x 40 sequential elements.
__global__ __launch_bounds__(256) void scan_kernel(
    const int* __restrict__ count, int* __restrict__ offsets,
    int* __restrict__ cursor, int n) {
  constexpr int PER = 40;  // 256*40 = 10240 >= 10000
  __shared__ int sums[256];
  const int t = threadIdx.x;
  const int base = t * PER;
  int loc[PER];
  int s = 0;
#pragma unroll
  for (int k = 0; k < PER; ++k) {
    const int i = base + k;
    const int v = (i < n) ? count[i] : 0;
    loc[k] = s;
    s += v;
  }
  sums[t] = s;
  __syncthreads();
#pragma unroll
  for (int off = 1; off < 256; off <<= 1) {
    const int add = (t >= off) ? sums[t - off] : 0;
    __syncthreads();
    sums[t] += add;
    __syncthreads();
  }
  const int carry = (t == 0) ? 0 : sums[t - 1];
#pragma unroll
  for (int k = 0; k < PER; ++k) {
    const int i = base + k;
    if (i < n) {
      const int o = carry + loc[k];
      offsets[i] = o;
      cursor[i]  = o;
    }
  }
  if (t == 255) offsets[n] = sums[255];
}

__global__ __launch_bounds__(256) void scatter_kernel(
    const int* __restrict__ src_arr, const int* __restrict__ dst_arr,
    int* __restrict__ cursor, int* __restrict__ src_sorted) {
  const int id = blockIdx.x * 256 + threadIdx.x;
  int s, d;
  if (id < N_EDGES)                { s = src_arr[id]; d = dst_arr[id]; }
  else if (id < N_EDGES + N_NODES) { s = d = id - N_EDGES; }
  else return;
  const int pos = atomicAdd(&cursor[d], 1);
  src_sorted[pos] = s;
}

// ---------------------------------------------------------------------------
// One block (256 thr) per destination node. alpha = exp(leaky(e))/sum
// (max-shift removable: |e| bounded, no overflow in fp32). Per 256-edge
// chunk: stage src idx + cooperative exp into LDS, then thread (h=t>>6,
// c=t&63) accumulates w*g[src,t] with coalesced row gathers.
// ---------------------------------------------------------------------------
__global__ __launch_bounds__(256) void aggregate_kernel(
    const float* __restrict__ g, const float* __restrict__ a_src,
    const float* __restrict__ a_dst, const int* __restrict__ offsets,
    const int* __restrict__ src_sorted, const float* __restrict__ bias_g,
    float* __restrict__ out) {
  const int i = blockIdx.x;
  const int t = threadIdx.x;
  const int start = offsets[i], end = offsets[i + 1];
  const int h = t >> 6;
  __shared__ float f_adst[4];
  __shared__ int   sidx_buf[256];
  __shared__ float w_buf[256 * 4];
  if (t < 4) f_adst[t] = a_dst[i * 4 + t];
  __syncthreads();
  const int   hh      = t & 3;
  const float adst_hh = f_adst[hh];
  const float* gt = g + t;

  float acc = 0.f, s_loc = 0.f;
  for (int cbase = start; cbase < end; cbase += 256) {
    const int cnt = min(256, end - cbase);
    if (t < cnt) sidx_buf[t] = src_sorted[cbase + t];
    __syncthreads();
    for (int jj = t >> 2; jj < cnt; jj += 64) {
      float e = a_src[sidx_buf[jj] * 4 + hh] + adst_hh;
      e = (e > 0.f) ? e : NEG_SLOPE * e;
      w_buf[jj * 4 + hh] = __expf(e);
    }
    __syncthreads();
#pragma unroll 4
    for (int jj = 0; jj < cnt; ++jj) {
      const float w = w_buf[jj * 4 + h];          // LDS broadcast
      s_loc += w;
      acc = fmaf(w, gt[(size_t)sidx_buf[jj] * HC], acc);
    }
    __syncthreads();
  }
  out[(size_t)i * HC + t] = acc / s_loc + bias_g[t];
}

// ---------------------------------------------------------------------------
extern "C" void kernel_launch(void* const* d_in, const int* in_sizes, int n_in,
                              void* d_out, int out_size, void* d_ws, size_t ws_size,
                              hipStream_t stream) {
  const float* x       = (const float*)d_in[0];
  const int*   ei      = (const int*)d_in[1];   // [2,E] int32: src then dst
  const float* W1      = (const float*)d_in[2];
  const float* b1      = (const float*)d_in[3];
  const float* W2      = (const float*)d_in[4];
  const float* b2      = (const float*)d_in[5];
  const float* Wg      = (const float*)d_in[6];
  const float* att_src = (const float*)d_in[7];
  const float* att_dst = (const float*)d_in[8];
  const float* bias_g  = (const float*)d_in[9];
  float* out = (float*)d_out;

  char* ws = (char*)d_ws;
  float* h1      = (float*)ws; ws += (size_t)N_NODES * DIM_HID * 4;
  float* g       = (float*)ws; ws += (size_t)N_NODES * HC * 4;
  float* Wfuse   = (float*)ws; ws += (size_t)DIM_HID * HC * 4;
  float* bfuse   = (float*)ws; ws += (size_t)HC * 4;
  float* a_src   = (float*)ws; ws += (size_t)N_NODES * 4 * 4;
  float* a_dst   = (float*)ws; ws += (size_t)N_NODES * 4 * 4;
  int* count     = (int*)ws;   ws += (size_t)N_NODES * 4;
  int* offsets   = (int*)ws;   ws += (size_t)(N_NODES + 4) * 4;
  int* cursor    = (int*)ws;   ws += (size_t)N_NODES * 4;
  int* src_sorted= (int*)ws;   ws += (size_t)(N_EDGES + N_NODES) * 4;

  hipMemsetAsync(count, 0, N_NODES * sizeof(int), stream);

  const dim3 blk(256);
  // tiny weight pre-fusion: Wfuse = W2 @ Wg, bfuse = b2 @ Wg
  gemm_kernel<32, false, false, false><<<dim3(2, 4), blk, 0, stream>>>(
      W2, Wg, nullptr, Wfuse, DIM_HID, HC, DIM_HID, nullptr, nullptr, nullptr, nullptr);
  bias_fuse_kernel<<<1, 256, 0, stream>>>(b2, Wg, bfuse);
  // encoder layer 1 (pipelined, BK=32 -> 16 K-iters)
  gemm_kernel<32, true, true, false><<<dim3(157, 2), blk, 0, stream>>>(
      x, W1, b1, h1, N_NODES, DIM_HID, DIM_IN, nullptr, nullptr, nullptr, nullptr);
  // fused encoder layer 2 + GAT linear, with attention-score epilogue
  gemm_kernel<32, false, true, true><<<dim3(157, 4), blk, 0, stream>>>(
      h1, Wfuse, bfuse, g, N_NODES, HC, DIM_HID, att_src, att_dst, a_src, a_dst);
  // CSR build (E edges + N self loops), bucketed by destination
  const int nEdgeBlk = (N_EDGES + N_NODES + 255) / 256;
  hist_kernel   <<<nEdgeBlk, blk, 0, stream>>>(ei + N_EDGES, count);
  scan_kernel   <<<1, 256, 0, stream>>>(count, offsets, cursor, N_NODES);
  scatter_kernel<<<nEdgeBlk, blk, 0, stream>>>(ei, ei + N_EDGES, cursor, src_sorted);
  // segment softmax + weighted aggregate, one block per node
  aggregate_kernel<<<N_NODES, blk, 0, stream>>>(g, a_src, a_dst, offsets, src_sorted, bias_g, out);
}

// Round 5
// 238.535 us; speedup vs baseline: 1.2302x; 1.2302x over previous
//
#include <hip/hip_runtime.h>

#define N_NODES 10000
#define N_EDGES 320000
#define DIM_IN  512
#define DIM_HID 128
#define HC      256   // HEADS*GC
#define NEG_SLOPE 0.2f

// ---------------------------------------------------------------------------
// fp32 GEMM, BM=BN=64, BK=16, 256 threads, 4x4 micro-tile.
// Single LDS buffer (8.4 KB) + REGISTER prefetch: store tile k to LDS, sync,
// issue k+1 global loads, compute k (loads overlap compute), sync. Lean on
// VGPR (~50) so occupancy is grid-limited, not resource-limited (R4 lesson:
// double-buffer LDS+BK32 -> 152 VGPR/33KB LDS -> 6.9% occupancy, regression).
// SPLITK: blockIdx.z selects a K-chunk of depth KS; partial written to
// C + z*M*N (no bias/act). Grid z-dim turns 314 blocks into 1256 (R3/R4
// lesson: gemm1 was TLP-starved at 1.2 blocks/CU).
// ATT: fused attention-score epilogue (one head per block since BN==64).
// ---------------------------------------------------------------------------
template<bool RELU, bool BIAS, bool ATT, bool SPLITK>
__global__ __launch_bounds__(256) void gemm_kernel(
    const float* __restrict__ A, const float* __restrict__ B,
    const float* __restrict__ bias, float* __restrict__ C,
    int M, int N, int K, int KS,   // K = A row stride; KS = depth per block
    const float* __restrict__ att_src, const float* __restrict__ att_dst,
    float* __restrict__ a_src, float* __restrict__ a_dst) {
  constexpr int BM = 64, BN = 64, BK = 16;
  __shared__ float Ast[BK][BM + 4];
  __shared__ float Bs[BK][BN];
  const int t  = threadIdx.x;
  const int tx = t & 15, ty = t >> 4;
  const int m0 = blockIdx.x * BM, n0 = blockIdx.y * BN;
  const int kbase = SPLITK ? blockIdx.z * KS : 0;
  const int ar = t >> 2, ac4 = (t & 3) * 4;   // A loader: row, k-offset
  const int br = t >> 4, bc4 = (t & 15) * 4;  // B loader: k-row, col-offset
  const int arow = m0 + ar;
  float acc[4][4] = {};
  float* Cb = SPLITK ? C + (size_t)blockIdx.z * M * N : C;

  float4 av, bv, avn, bvn;
  auto gload = [&](int k0, float4& a4, float4& b4) {
    a4 = (arow < M) ? *(const float4*)(A + (size_t)arow * K + k0 + ac4)
                    : make_float4(0.f, 0.f, 0.f, 0.f);
    b4 = *(const float4*)(B + (size_t)(k0 + br) * N + n0 + bc4);
  };

  const int k_end = kbase + KS;
  gload(kbase, av, bv);
  for (int k0 = kbase; k0 < k_end; k0 += BK) {
    Ast[ac4 + 0][ar] = av.x; Ast[ac4 + 1][ar] = av.y;
    Ast[ac4 + 2][ar] = av.z; Ast[ac4 + 3][ar] = av.w;
    *(float4*)&Bs[br][bc4] = bv;
    __syncthreads();
    if (k0 + BK < k_end) gload(k0 + BK, avn, bvn);  // overlaps compute below
#pragma unroll
    for (int kk = 0; kk < BK; ++kk) {
      const float4 a = *(const float4*)&Ast[kk][ty * 4];
      const float4 b = *(const float4*)&Bs[kk][tx * 4];
      const float as[4] = {a.x, a.y, a.z, a.w};
      const float bs[4] = {b.x, b.y, b.z, b.w};
#pragma unroll
      for (int i = 0; i < 4; ++i)
#pragma unroll
        for (int j = 0; j < 4; ++j) acc[i][j] = fmaf(as[i], bs[j], acc[i][j]);
    }
    __syncthreads();
    av = avn; bv = bvn;
  }

  float4 bvv = make_float4(0.f, 0.f, 0.f, 0.f);
  if (BIAS) bvv = *(const float4*)(bias + n0 + tx * 4);
#pragma unroll
  for (int i = 0; i < 4; ++i) {
    const int row = m0 + ty * 4 + i;
    if (row < M) {
      float4 v;
      v.x = acc[i][0] + bvv.x; v.y = acc[i][1] + bvv.y;
      v.z = acc[i][2] + bvv.z; v.w = acc[i][3] + bvv.w;
      if (RELU) {
        v.x = fmaxf(v.x, 0.f); v.y = fmaxf(v.y, 0.f);
        v.z = fmaxf(v.z, 0.f); v.w = fmaxf(v.w, 0.f);
      }
      *(float4*)(Cb + (size_t)row * N + n0 + tx * 4) = v;
    }
  }

  if (ATT) {
    const int hh = n0 >> 6;   // one head per 64-col block
#pragma unroll
    for (int i = 0; i < 4; ++i) {
      float ps = 0.f, pd = 0.f;
#pragma unroll
      for (int j = 0; j < 4; ++j) {
        const int c = tx * 4 + j;
        ps = fmaf(acc[i][j], att_src[hh * 64 + c], ps);
        pd = fmaf(acc[i][j], att_dst[hh * 64 + c], pd);
      }
#pragma unroll
      for (int off = 8; off > 0; off >>= 1) {
        ps += __shfl_down(ps, off, 16);
        pd += __shfl_down(pd, off, 16);
      }
      if (tx == 0) {
        const int row = m0 + ty * 4 + i;
        if (row < M) {
          a_src[row * 4 + hh] = ps;
          a_dst[row * 4 + hh] = pd;
        }
      }
    }
  }
}

// h1 = relu(sum_z part[z] + b1), float4-vectorized over [N_NODES, DIM_HID]
__global__ __launch_bounds__(256) void reduce_relu_bias_kernel(
    const float* __restrict__ part, const float* __restrict__ b1,
    float* __restrict__ h1) {
  const int id = blockIdx.x * 256 + threadIdx.x;   // float4 index
  constexpr int TOT = N_NODES * DIM_HID / 4;
  if (id >= TOT) return;
  const float4* p = (const float4*)part;
  float4 v = p[id];
#pragma unroll
  for (int s = 1; s < 4; ++s) {
    const float4 w = p[id + (size_t)s * TOT];
    v.x += w.x; v.y += w.y; v.z += w.z; v.w += w.w;
  }
  const float4 bv = *(const float4*)(b1 + (id & 31) * 4);
  v.x = fmaxf(v.x + bv.x, 0.f); v.y = fmaxf(v.y + bv.y, 0.f);
  v.z = fmaxf(v.z + bv.z, 0.f); v.w = fmaxf(v.w + bv.w, 0.f);
  ((float4*)h1)[id] = v;
}

// bfuse[c] = sum_k b2[k] * Wg[k,c]
__global__ __launch_bounds__(256) void bias_fuse_kernel(
    const float* __restrict__ b2, const float* __restrict__ Wg,
    float* __restrict__ bfuse) {
  const int c = threadIdx.x;
  float acc = 0.f;
  for (int k = 0; k < DIM_HID; ++k) acc = fmaf(b2[k], Wg[k * HC + c], acc);
  bfuse[c] = acc;
}

// ---------------------------------------------------------------------------
// CSR build: histogram of dst (E real edges + N self loops)
// ---------------------------------------------------------------------------
__global__ __launch_bounds__(256) void hist_kernel(
    const int* __restrict__ dst_arr, int* __restrict__ count) {
  const int id = blockIdx.x * 256 + threadIdx.x;
  if (id < N_EDGES)                 atomicAdd(&count[dst_arr[id]], 1);
  else if (id < N_EDGES + N_NODES)  atomicAdd(&count[id - N_EDGES], 1);
}

// Work-efficient single-block scan: 256 threads x 40 sequential elements.
__global__ __launch_bounds__(256) void scan_kernel(
    const int* __restrict__ count, int* __restrict__ offsets,
    int* __restrict__ cursor, int n) {
  constexpr int PER = 40;  // 256*40 = 10240 >= 10000
  __shared__ int sums[256];
  const int t = threadIdx.x;
  const int base = t * PER;
  int loc[PER];
  int s = 0;
#pragma unroll
  for (int k = 0; k < PER; ++k) {
    const int i = base + k;
    const int v = (i < n) ? count[i] : 0;
    loc[k] = s;
    s += v;
  }
  sums[t] = s;
  __syncthreads();
#pragma unroll
  for (int off = 1; off < 256; off <<= 1) {
    const int add = (t >= off) ? sums[t - off] : 0;
    __syncthreads();
    sums[t] += add;
    __syncthreads();
  }
  const int carry = (t == 0) ? 0 : sums[t - 1];
#pragma unroll
  for (int k = 0; k < PER; ++k) {
    const int i = base + k;
    if (i < n) {
      const int o = carry + loc[k];
      offsets[i] = o;
      cursor[i]  = o;
    }
  }
  if (t == 255) offsets[n] = sums[255];
}

__global__ __launch_bounds__(256) void scatter_kernel(
    const int* __restrict__ src_arr, const int* __restrict__ dst_arr,
    int* __restrict__ cursor, int* __restrict__ src_sorted) {
  const int id = blockIdx.x * 256 + threadIdx.x;
  int s, d;
  if (id < N_EDGES)                { s = src_arr[id]; d = dst_arr[id]; }
  else if (id < N_EDGES + N_NODES) { s = d = id - N_EDGES; }
  else return;
  const int pos = atomicAdd(&cursor[d], 1);
  src_sorted[pos] = s;
}

// ---------------------------------------------------------------------------
// One block (256 thr) per destination node. alpha = exp(leaky(e))/sum
// (max-shift removable: |e| bounded, no overflow in fp32). Per 256-edge
// chunk: stage src idx + cooperative exp into LDS, then thread (h=t>>6,
// c=t&63) accumulates w*g[src,t] with coalesced row gathers.
// ---------------------------------------------------------------------------
__global__ __launch_bounds__(256) void aggregate_kernel(
    const float* __restrict__ g, const float* __restrict__ a_src,
    const float* __restrict__ a_dst, const int* __restrict__ offsets,
    const int* __restrict__ src_sorted, const float* __restrict__ bias_g,
    float* __restrict__ out) {
  const int i = blockIdx.x;
  const int t = threadIdx.x;
  const int start = offsets[i], end = offsets[i + 1];
  const int h = t >> 6;
  __shared__ float f_adst[4];
  __shared__ int   sidx_buf[256];
  __shared__ float w_buf[256 * 4];
  if (t < 4) f_adst[t] = a_dst[i * 4 + t];
  __syncthreads();
  const int   hh      = t & 3;
  const float adst_hh = f_adst[hh];
  const float* gt = g + t;

  float acc = 0.f, s_loc = 0.f;
  for (int cbase = start; cbase < end; cbase += 256) {
    const int cnt = min(256, end - cbase);
    if (t < cnt) sidx_buf[t] = src_sorted[cbase + t];
    __syncthreads();
    for (int jj = t >> 2; jj < cnt; jj += 64) {
      float e = a_src[sidx_buf[jj] * 4 + hh] + adst_hh;
      e = (e > 0.f) ? e : NEG_SLOPE * e;
      w_buf[jj * 4 + hh] = __expf(e);
    }
    __syncthreads();
#pragma unroll 4
    for (int jj = 0; jj < cnt; ++jj) {
      const float w = w_buf[jj * 4 + h];          // LDS broadcast
      s_loc += w;
      acc = fmaf(w, gt[(size_t)sidx_buf[jj] * HC], acc);
    }
    __syncthreads();
  }
  out[(size_t)i * HC + t] = acc / s_loc + bias_g[t];
}

// ---------------------------------------------------------------------------
extern "C" void kernel_launch(void* const* d_in, const int* in_sizes, int n_in,
                              void* d_out, int out_size, void* d_ws, size_t ws_size,
                              hipStream_t stream) {
  const float* x       = (const float*)d_in[0];
  const int*   ei      = (const int*)d_in[1];   // [2,E] int32: src then dst
  const float* W1      = (const float*)d_in[2];
  const float* b1      = (const float*)d_in[3];
  const float* W2      = (const float*)d_in[4];
  const float* b2      = (const float*)d_in[5];
  const float* Wg      = (const float*)d_in[6];
  const float* att_src = (const float*)d_in[7];
  const float* att_dst = (const float*)d_in[8];
  const float* bias_g  = (const float*)d_in[9];
  float* out = (float*)d_out;

  char* ws = (char*)d_ws;
  float* h1      = (float*)ws; ws += (size_t)N_NODES * DIM_HID * 4;
  float* h1p     = (float*)ws; ws += (size_t)4 * N_NODES * DIM_HID * 4;  // split-K partials
  float* g       = (float*)ws; ws += (size_t)N_NODES * HC * 4;
  float* Wfuse   = (float*)ws; ws += (size_t)DIM_HID * HC * 4;
  float* bfuse   = (float*)ws; ws += (size_t)HC * 4;
  float* a_src   = (float*)ws; ws += (size_t)N_NODES * 4 * 4;
  float* a_dst   = (float*)ws; ws += (size_t)N_NODES * 4 * 4;
  int* count     = (int*)ws;   ws += (size_t)N_NODES * 4;
  int* offsets   = (int*)ws;   ws += (size_t)(N_NODES + 4) * 4;
  int* cursor    = (int*)ws;   ws += (size_t)N_NODES * 4;
  int* src_sorted= (int*)ws;   ws += (size_t)(N_EDGES + N_NODES) * 4;

  hipMemsetAsync(count, 0, N_NODES * sizeof(int), stream);

  const dim3 blk(256);
  // tiny weight pre-fusion: Wfuse = W2 @ Wg, bfuse = b2 @ Wg
  gemm_kernel<false, false, false, false><<<dim3(2, 4), blk, 0, stream>>>(
      W2, Wg, nullptr, Wfuse, DIM_HID, HC, DIM_HID, DIM_HID,
      nullptr, nullptr, nullptr, nullptr);
  bias_fuse_kernel<<<1, 256, 0, stream>>>(b2, Wg, bfuse);
  // encoder layer 1, split-K=4: 157*2*4 = 1256 blocks
  gemm_kernel<false, false, false, true><<<dim3(157, 2, 4), blk, 0, stream>>>(
      x, W1, nullptr, h1p, N_NODES, DIM_HID, DIM_IN, DIM_IN / 4,
      nullptr, nullptr, nullptr, nullptr);
  reduce_relu_bias_kernel<<<(N_NODES * DIM_HID / 4 + 255) / 256, blk, 0, stream>>>(
      h1p, b1, h1);
  // fused encoder layer 2 + GAT linear, with attention-score epilogue
  gemm_kernel<false, true, true, false><<<dim3(157, 4), blk, 0, stream>>>(
      h1, Wfuse, bfuse, g, N_NODES, HC, DIM_HID, DIM_HID,
      att_src, att_dst, a_src, a_dst);
  // CSR build (E edges + N self loops), bucketed by destination
  const int nEdgeBlk = (N_EDGES + N_NODES + 255) / 256;
  hist_kernel   <<<nEdgeBlk, blk, 0, stream>>>(ei + N_EDGES, count);
  scan_kernel   <<<1, 256, 0, stream>>>(count, offsets, cursor, N_NODES);
  scatter_kernel<<<nEdgeBlk, blk, 0, stream>>>(ei, ei + N_EDGES, cursor, src_sorted);
  // segment softmax + weighted aggregate, one block per node
  aggregate_kernel<<<N_NODES, blk, 0, stream>>>(g, a_src, a_dst, offsets, src_sorted, bias_g, out);
}

// Round 6
// 226.084 us; speedup vs baseline: 1.2979x; 1.0551x over previous
//
#include <hip/hip_runtime.h>

#define N_NODES 10000
#define N_EDGES 320000
#define DIM_IN  512
#define DIM_HID 128
#define HC      256   // HEADS*GC
#define NEG_SLOPE 0.2f

__device__ __forceinline__ unsigned short f2bf(float x) {  // RNE fp32->bf16
  unsigned int u = __float_as_uint(x);
  u += 0x7FFFu + ((u >> 16) & 1u);
  return (unsigned short)(u >> 16);
}
__device__ __forceinline__ float bf2f(unsigned short s) {
  return __uint_as_float(((unsigned int)s) << 16);
}

// ---------------------------------------------------------------------------
// fp32 GEMM, BM=BN=64, BK=16, 256 threads, 4x4 micro-tile.
// Single LDS buffer (8.4 KB) + register prefetch (R4 lesson: fat double
// buffering killed occupancy; R5 confirmed this lean shape works).
// SPLITK: blockIdx.z selects K-chunk, partial -> C + z*M*N.
// ATT: fused attention-score epilogue (one head per block since BN==64).
// OUTBF16: epilogue packs C to bf16 (ushort4) — used for g, whose only
// consumer is the edge gather (halves gather bytes; 5 MB fits XCD L2).
// ---------------------------------------------------------------------------
template<bool RELU, bool BIAS, bool ATT, bool SPLITK, bool OUTBF16>
__global__ __launch_bounds__(256) void gemm_kernel(
    const float* __restrict__ A, const float* __restrict__ B,
    const float* __restrict__ bias, void* __restrict__ Cv,
    int M, int N, int K, int KS,   // K = A row stride; KS = depth per block
    const float* __restrict__ att_src, const float* __restrict__ att_dst,
    float* __restrict__ a_src, float* __restrict__ a_dst) {
  constexpr int BM = 64, BN = 64, BK = 16;
  __shared__ float Ast[BK][BM + 4];
  __shared__ float Bs[BK][BN];
  const int t  = threadIdx.x;
  const int tx = t & 15, ty = t >> 4;
  const int m0 = blockIdx.x * BM, n0 = blockIdx.y * BN;
  const int kbase = SPLITK ? blockIdx.z * KS : 0;
  const int ar = t >> 2, ac4 = (t & 3) * 4;   // A loader: row, k-offset
  const int br = t >> 4, bc4 = (t & 15) * 4;  // B loader: k-row, col-offset
  const int arow = m0 + ar;
  float acc[4][4] = {};

  float4 av, bv, avn, bvn;
  auto gload = [&](int k0, float4& a4, float4& b4) {
    a4 = (arow < M) ? *(const float4*)(A + (size_t)arow * K + k0 + ac4)
                    : make_float4(0.f, 0.f, 0.f, 0.f);
    b4 = *(const float4*)(B + (size_t)(k0 + br) * N + n0 + bc4);
  };

  const int k_end = kbase + KS;
  gload(kbase, av, bv);
  for (int k0 = kbase; k0 < k_end; k0 += BK) {
    Ast[ac4 + 0][ar] = av.x; Ast[ac4 + 1][ar] = av.y;
    Ast[ac4 + 2][ar] = av.z; Ast[ac4 + 3][ar] = av.w;
    *(float4*)&Bs[br][bc4] = bv;
    __syncthreads();
    if (k0 + BK < k_end) gload(k0 + BK, avn, bvn);  // overlaps compute below
#pragma unroll
    for (int kk = 0; kk < BK; ++kk) {
      const float4 a = *(const float4*)&Ast[kk][ty * 4];
      const float4 b = *(const float4*)&Bs[kk][tx * 4];
      const float as[4] = {a.x, a.y, a.z, a.w};
      const float bs[4] = {b.x, b.y, b.z, b.w};
#pragma unroll
      for (int i = 0; i < 4; ++i)
#pragma unroll
        for (int j = 0; j < 4; ++j) acc[i][j] = fmaf(as[i], bs[j], acc[i][j]);
    }
    __syncthreads();
    av = avn; bv = bvn;
  }

  float4 bvv = make_float4(0.f, 0.f, 0.f, 0.f);
  if (BIAS) bvv = *(const float4*)(bias + n0 + tx * 4);
#pragma unroll
  for (int i = 0; i < 4; ++i) {
    const int row = m0 + ty * 4 + i;
    if (row < M) {
      float4 v;
      v.x = acc[i][0] + bvv.x; v.y = acc[i][1] + bvv.y;
      v.z = acc[i][2] + bvv.z; v.w = acc[i][3] + bvv.w;
      if (RELU) {
        v.x = fmaxf(v.x, 0.f); v.y = fmaxf(v.y, 0.f);
        v.z = fmaxf(v.z, 0.f); v.w = fmaxf(v.w, 0.f);
      }
      if (OUTBF16) {
        ushort4 sv;
        sv.x = f2bf(v.x); sv.y = f2bf(v.y); sv.z = f2bf(v.z); sv.w = f2bf(v.w);
        *(ushort4*)((unsigned short*)Cv + (size_t)row * N + n0 + tx * 4) = sv;
      } else {
        float* Cb = SPLITK ? (float*)Cv + (size_t)blockIdx.z * M * N : (float*)Cv;
        *(float4*)(Cb + (size_t)row * N + n0 + tx * 4) = v;
      }
    }
  }

  if (ATT) {
    const int hh = n0 >> 6;   // one head per 64-col block
#pragma unroll
    for (int i = 0; i < 4; ++i) {
      float ps = 0.f, pd = 0.f;
#pragma unroll
      for (int j = 0; j < 4; ++j) {
        const int c = tx * 4 + j;
        ps = fmaf(acc[i][j], att_src[hh * 64 + c], ps);
        pd = fmaf(acc[i][j], att_dst[hh * 64 + c], pd);
      }
#pragma unroll
      for (int off = 8; off > 0; off >>= 1) {
        ps += __shfl_down(ps, off, 16);
        pd += __shfl_down(pd, off, 16);
      }
      if (tx == 0) {
        const int row = m0 + ty * 4 + i;
        if (row < M) {
          a_src[row * 4 + hh] = ps;
          a_dst[row * 4 + hh] = pd;
        }
      }
    }
  }
}

// h1 = relu(sum_z part[z] + b1), float4-vectorized over [N_NODES, DIM_HID]
__global__ __launch_bounds__(256) void reduce_relu_bias_kernel(
    const float* __restrict__ part, const float* __restrict__ b1,
    float* __restrict__ h1) {
  const int id = blockIdx.x * 256 + threadIdx.x;   // float4 index
  constexpr int TOT = N_NODES * DIM_HID / 4;
  if (id >= TOT) return;
  const float4* p = (const float4*)part;
  float4 v = p[id];
#pragma unroll
  for (int s = 1; s < 4; ++s) {
    const float4 w = p[id + (size_t)s * TOT];
    v.x += w.x; v.y += w.y; v.z += w.z; v.w += w.w;
  }
  const float4 bv = *(const float4*)(b1 + (id & 31) * 4);
  v.x = fmaxf(v.x + bv.x, 0.f); v.y = fmaxf(v.y + bv.y, 0.f);
  v.z = fmaxf(v.z + bv.z, 0.f); v.w = fmaxf(v.w + bv.w, 0.f);
  ((float4*)h1)[id] = v;
}

// bfuse[c] = sum_k b2[k] * Wg[k,c]
__global__ __launch_bounds__(256) void bias_fuse_kernel(
    const float* __restrict__ b2, const float* __restrict__ Wg,
    float* __restrict__ bfuse) {
  const int c = threadIdx.x;
  float acc = 0.f;
  for (int k = 0; k < DIM_HID; ++k) acc = fmaf(b2[k], Wg[k * HC + c], acc);
  bfuse[c] = acc;
}

// count[i] = 1 (self-loop pre-counted; replaces memset + 10K atomics)
__global__ __launch_bounds__(256) void init_count_kernel(int* __restrict__ count) {
  const int i = blockIdx.x * 256 + threadIdx.x;
  if (i < N_NODES) count[i] = 1;
}

// histogram of dst over the E real edges
__global__ __launch_bounds__(256) void hist_kernel(
    const int* __restrict__ dst_arr, int* __restrict__ count) {
  const int id = blockIdx.x * 256 + threadIdx.x;
  if (id < N_EDGES) atomicAdd(&count[dst_arr[id]], 1);
}

// Work-efficient single-block scan: 256 threads x 40 sequential elements.
__global__ __launch_bounds__(256) void scan_kernel(
    const int* __restrict__ count, int* __restrict__ offsets,
    int* __restrict__ cursor, int n) {
  constexpr int PER = 40;  // 256*40 = 10240 >= 10000
  __shared__ int sums[256];
  const int t = threadIdx.x;
  const int base = t * PER;
  int loc[PER];
  int s = 0;
#pragma unroll
  for (int k = 0; k < PER; ++k) {
    const int i = base + k;
    const int v = (i < n) ? count[i] : 0;
    loc[k] = s;
    s += v;
  }
  sums[t] = s;
  __syncthreads();
#pragma unroll
  for (int off = 1; off < 256; off <<= 1) {
    const int add = (t >= off) ? sums[t - off] : 0;
    __syncthreads();
    sums[t] += add;
    __syncthreads();
  }
  const int carry = (t == 0) ? 0 : sums[t - 1];
#pragma unroll
  for (int k = 0; k < PER; ++k) {
    const int i = base + k;
    if (i < n) {
      const int o = carry + loc[k];
      offsets[i] = o;
      cursor[i]  = o;
    }
  }
  if (t == 255) offsets[n] = sums[255];
}

__global__ __launch_bounds__(256) void scatter_kernel(
    const int* __restrict__ src_arr, const int* __restrict__ dst_arr,
    int* __restrict__ cursor, int* __restrict__ src_sorted) {
  const int id = blockIdx.x * 256 + threadIdx.x;
  int s, d;
  if (id < N_EDGES)                { s = src_arr[id]; d = dst_arr[id]; }
  else if (id < N_EDGES + N_NODES) { s = d = id - N_EDGES; }
  else return;
  const int pos = atomicAdd(&cursor[d], 1);
  src_sorted[pos] = s;
}

// ---------------------------------------------------------------------------
// One block (256 thr) per destination node; g is bf16 (2 B/chan) so the
// random row gather moves half the bytes and g (5 MB) ~fits per-XCD L2.
// alpha = exp(leaky(e))/sum (max-shift removable: |e| bounded, fp32-safe).
// ---------------------------------------------------------------------------
__global__ __launch_bounds__(256) void aggregate_kernel(
    const unsigned short* __restrict__ g, const float* __restrict__ a_src,
    const float* __restrict__ a_dst, const int* __restrict__ offsets,
    const int* __restrict__ src_sorted, const float* __restrict__ bias_g,
    float* __restrict__ out) {
  const int i = blockIdx.x;
  const int t = threadIdx.x;
  const int start = offsets[i], end = offsets[i + 1];
  const int h = t >> 6;
  __shared__ float f_adst[4];
  __shared__ int   sidx_buf[256];
  __shared__ float w_buf[256 * 4];
  if (t < 4) f_adst[t] = a_dst[i * 4 + t];
  __syncthreads();
  const int   hh      = t & 3;
  const float adst_hh = f_adst[hh];
  const unsigned short* gt = g + t;

  float acc = 0.f, s_loc = 0.f;
  for (int cbase = start; cbase < end; cbase += 256) {
    const int cnt = min(256, end - cbase);
    if (t < cnt) sidx_buf[t] = src_sorted[cbase + t];
    __syncthreads();
    for (int jj = t >> 2; jj < cnt; jj += 64) {
      float e = a_src[sidx_buf[jj] * 4 + hh] + adst_hh;
      e = (e > 0.f) ? e : NEG_SLOPE * e;
      w_buf[jj * 4 + hh] = __expf(e);
    }
    __syncthreads();
#pragma unroll 8
    for (int jj = 0; jj < cnt; ++jj) {
      const float w = w_buf[jj * 4 + h];          // LDS broadcast
      s_loc += w;
      acc = fmaf(w, bf2f(gt[(size_t)sidx_buf[jj] * HC]), acc);
    }
    __syncthreads();
  }
  out[(size_t)i * HC + t] = acc / s_loc + bias_g[t];
}

// ---------------------------------------------------------------------------
extern "C" void kernel_launch(void* const* d_in, const int* in_sizes, int n_in,
                              void* d_out, int out_size, void* d_ws, size_t ws_size,
                              hipStream_t stream) {
  const float* x       = (const float*)d_in[0];
  const int*   ei      = (const int*)d_in[1];   // [2,E] int32: src then dst
  const float* W1      = (const float*)d_in[2];
  const float* b1      = (const float*)d_in[3];
  const float* W2      = (const float*)d_in[4];
  const float* b2      = (const float*)d_in[5];
  const float* Wg      = (const float*)d_in[6];
  const float* att_src = (const float*)d_in[7];
  const float* att_dst = (const float*)d_in[8];
  const float* bias_g  = (const float*)d_in[9];
  float* out = (float*)d_out;

  char* ws = (char*)d_ws;
  float* h1      = (float*)ws; ws += (size_t)N_NODES * DIM_HID * 4;
  float* h1p     = (float*)ws; ws += (size_t)4 * N_NODES * DIM_HID * 4;  // split-K partials
  unsigned short* g = (unsigned short*)ws; ws += (size_t)N_NODES * HC * 2;
  float* Wfuse   = (float*)ws; ws += (size_t)DIM_HID * HC * 4;
  float* bfuse   = (float*)ws; ws += (size_t)HC * 4;
  float* a_src   = (float*)ws; ws += (size_t)N_NODES * 4 * 4;
  float* a_dst   = (float*)ws; ws += (size_t)N_NODES * 4 * 4;
  int* count     = (int*)ws;   ws += (size_t)N_NODES * 4;
  int* offsets   = (int*)ws;   ws += (size_t)(N_NODES + 4) * 4;
  int* cursor    = (int*)ws;   ws += (size_t)N_NODES * 4;
  int* src_sorted= (int*)ws;   ws += (size_t)(N_EDGES + N_NODES) * 4;

  const dim3 blk(256);
  // tiny weight pre-fusion: Wfuse = W2 @ Wg, bfuse = b2 @ Wg
  gemm_kernel<false, false, false, false, false><<<dim3(2, 4), blk, 0, stream>>>(
      W2, Wg, nullptr, Wfuse, DIM_HID, HC, DIM_HID, DIM_HID,
      nullptr, nullptr, nullptr, nullptr);
  bias_fuse_kernel<<<1, 256, 0, stream>>>(b2, Wg, bfuse);
  // encoder layer 1, split-K=4: 157*2*4 = 1256 blocks
  gemm_kernel<false, false, false, true, false><<<dim3(157, 2, 4), blk, 0, stream>>>(
      x, W1, nullptr, h1p, N_NODES, DIM_HID, DIM_IN, DIM_IN / 4,
      nullptr, nullptr, nullptr, nullptr);
  reduce_relu_bias_kernel<<<(N_NODES * DIM_HID / 4 + 255) / 256, blk, 0, stream>>>(
      h1p, b1, h1);
  // fused encoder layer 2 + GAT linear -> bf16 g, with attention epilogue
  gemm_kernel<false, true, true, false, true><<<dim3(157, 4), blk, 0, stream>>>(
      h1, Wfuse, bfuse, g, N_NODES, HC, DIM_HID, DIM_HID,
      att_src, att_dst, a_src, a_dst);
  // CSR build (E edges + N self loops), bucketed by destination
  init_count_kernel<<<(N_NODES + 255) / 256, blk, 0, stream>>>(count);
  hist_kernel<<<(N_EDGES + 255) / 256, blk, 0, stream>>>(ei + N_EDGES, count);
  scan_kernel<<<1, 256, 0, stream>>>(count, offsets, cursor, N_NODES);
  const int nEdgeBlk = (N_EDGES + N_NODES + 255) / 256;
  scatter_kernel<<<nEdgeBlk, blk, 0, stream>>>(ei, ei + N_EDGES, cursor, src_sorted);
  // segment softmax + weighted aggregate, one block per node
  aggregate_kernel<<<N_NODES, blk, 0, stream>>>(g, a_src, a_dst, offsets, src_sorted, bias_g, out);
}

// Round 7
// 218.183 us; speedup vs baseline: 1.3449x; 1.0362x over previous
//
#include <hip/hip_runtime.h>

#define N_NODES 10000
#define N_EDGES 320000
#define DIM_IN  512
#define DIM_HID 128
#define HC      256   // HEADS*GC
#define NEG_SLOPE 0.2f

__device__ __forceinline__ unsigned short f2bf(float x) {  // RNE fp32->bf16
  unsigned int u = __float_as_uint(x);
  u += 0x7FFFu + ((u >> 16) & 1u);
  return (unsigned short)(u >> 16);
}
__device__ __forceinline__ float bf2f(unsigned short s) {
  return __uint_as_float(((unsigned int)s) << 16);
}

// ---------------------------------------------------------------------------
// fp32 GEMM, BM=BN=64, BK=16, 256 threads, 4x4 micro-tile.
// Single LDS buffer + register prefetch (R4 lesson: fat double-buffer killed
// occupancy; this lean shape is the R5/R6 winner).
// SPLITK: blockIdx.z selects K-chunk, partial -> C + z*M*N.
// ATT: fused attention-score epilogue (one head per block since BN==64).
// OUTBF16: epilogue packs C to bf16 (only consumer is the edge gather).
// XB: virtual extra A row (M-1) read from xrow (b2) -> fuses bfuse=b2@Wg
//     into the Wfuse GEMM (bfuse allocated contiguously after Wfuse).
// ZC: preamble zeroes zero_buf (count) -> kills the init_count launch.
// ---------------------------------------------------------------------------
template<bool RELU, bool BIAS, bool ATT, bool SPLITK, bool OUTBF16, bool XB, bool ZC>
__global__ __launch_bounds__(256) void gemm_kernel(
    const float* __restrict__ A, const float* __restrict__ B,
    const float* __restrict__ bias, void* __restrict__ Cv,
    int M, int N, int K, int KS,   // K = A row stride; KS = depth per block
    const float* __restrict__ att_src, const float* __restrict__ att_dst,
    float* __restrict__ a_src, float* __restrict__ a_dst,
    const float* __restrict__ xrow, int* __restrict__ zero_buf) {
  constexpr int BM = 64, BN = 64, BK = 16;
  __shared__ float Ast[BK][BM + 4];
  __shared__ float Bs[BK][BN];
  const int t  = threadIdx.x;
  if (ZC) {
    const int flat = (blockIdx.x * gridDim.y + blockIdx.y) * 256 + t;
    if (flat < (N_NODES + 3) / 4) ((int4*)zero_buf)[flat] = make_int4(0, 0, 0, 0);
  }
  const int tx = t & 15, ty = t >> 4;
  const int m0 = blockIdx.x * BM, n0 = blockIdx.y * BN;
  const int kbase = SPLITK ? blockIdx.z * KS : 0;
  const int ar = t >> 2, ac4 = (t & 3) * 4;   // A loader: row, k-offset
  const int br = t >> 4, bc4 = (t & 15) * 4;  // B loader: k-row, col-offset
  const int arow = m0 + ar;
  float acc[4][4] = {};

  float4 av, bv, avn, bvn;
  auto gload = [&](int k0, float4& a4, float4& b4) {
    if (XB) {
      if (arow < M - 1)       a4 = *(const float4*)(A + (size_t)arow * K + k0 + ac4);
      else if (arow == M - 1) a4 = *(const float4*)(xrow + k0 + ac4);
      else                    a4 = make_float4(0.f, 0.f, 0.f, 0.f);
    } else {
      a4 = (arow < M) ? *(const float4*)(A + (size_t)arow * K + k0 + ac4)
                      : make_float4(0.f, 0.f, 0.f, 0.f);
    }
    b4 = *(const float4*)(B + (size_t)(k0 + br) * N + n0 + bc4);
  };

  const int k_end = kbase + KS;
  gload(kbase, av, bv);
  for (int k0 = kbase; k0 < k_end; k0 += BK) {
    Ast[ac4 + 0][ar] = av.x; Ast[ac4 + 1][ar] = av.y;
    Ast[ac4 + 2][ar] = av.z; Ast[ac4 + 3][ar] = av.w;
    *(float4*)&Bs[br][bc4] = bv;
    __syncthreads();
    if (k0 + BK < k_end) gload(k0 + BK, avn, bvn);  // overlaps compute below
#pragma unroll
    for (int kk = 0; kk < BK; ++kk) {
      const float4 a = *(const float4*)&Ast[kk][ty * 4];
      const float4 b = *(const float4*)&Bs[kk][tx * 4];
      const float as[4] = {a.x, a.y, a.z, a.w};
      const float bs[4] = {b.x, b.y, b.z, b.w};
#pragma unroll
      for (int i = 0; i < 4; ++i)
#pragma unroll
        for (int j = 0; j < 4; ++j) acc[i][j] = fmaf(as[i], bs[j], acc[i][j]);
    }
    __syncthreads();
    av = avn; bv = bvn;
  }

  float4 bvv = make_float4(0.f, 0.f, 0.f, 0.f);
  if (BIAS) bvv = *(const float4*)(bias + n0 + tx * 4);
#pragma unroll
  for (int i = 0; i < 4; ++i) {
    const int row = m0 + ty * 4 + i;
    if (row < M) {
      float4 v;
      v.x = acc[i][0] + bvv.x; v.y = acc[i][1] + bvv.y;
      v.z = acc[i][2] + bvv.z; v.w = acc[i][3] + bvv.w;
      if (RELU) {
        v.x = fmaxf(v.x, 0.f); v.y = fmaxf(v.y, 0.f);
        v.z = fmaxf(v.z, 0.f); v.w = fmaxf(v.w, 0.f);
      }
      if (OUTBF16) {
        ushort4 sv;
        sv.x = f2bf(v.x); sv.y = f2bf(v.y); sv.z = f2bf(v.z); sv.w = f2bf(v.w);
        *(ushort4*)((unsigned short*)Cv + (size_t)row * N + n0 + tx * 4) = sv;
      } else {
        float* Cb = SPLITK ? (float*)Cv + (size_t)blockIdx.z * M * N : (float*)Cv;
        *(float4*)(Cb + (size_t)row * N + n0 + tx * 4) = v;
      }
    }
  }

  if (ATT) {
    const int hh = n0 >> 6;   // one head per 64-col block
#pragma unroll
    for (int i = 0; i < 4; ++i) {
      float ps = 0.f, pd = 0.f;
#pragma unroll
      for (int j = 0; j < 4; ++j) {
        const int c = tx * 4 + j;
        ps = fmaf(acc[i][j], att_src[hh * 64 + c], ps);
        pd = fmaf(acc[i][j], att_dst[hh * 64 + c], pd);
      }
#pragma unroll
      for (int off = 8; off > 0; off >>= 1) {
        ps += __shfl_down(ps, off, 16);
        pd += __shfl_down(pd, off, 16);
      }
      if (tx == 0) {
        const int row = m0 + ty * 4 + i;
        if (row < M) {
          a_src[row * 4 + hh] = ps;
          a_dst[row * 4 + hh] = pd;
        }
      }
    }
  }
}

// h1 = relu(sum_z part[z] + b1), float4-vectorized over [N_NODES, DIM_HID]
__global__ __launch_bounds__(256) void reduce_relu_bias_kernel(
    const float* __restrict__ part, const float* __restrict__ b1,
    float* __restrict__ h1) {
  const int id = blockIdx.x * 256 + threadIdx.x;   // float4 index
  constexpr int TOT = N_NODES * DIM_HID / 4;
  if (id >= TOT) return;
  const float4* p = (const float4*)part;
  float4 v = p[id];
#pragma unroll
  for (int s = 1; s < 4; ++s) {
    const float4 w = p[id + (size_t)s * TOT];
    v.x += w.x; v.y += w.y; v.z += w.z; v.w += w.w;
  }
  const float4 bv = *(const float4*)(b1 + (id & 31) * 4);
  v.x = fmaxf(v.x + bv.x, 0.f); v.y = fmaxf(v.y + bv.y, 0.f);
  v.z = fmaxf(v.z + bv.z, 0.f); v.w = fmaxf(v.w + bv.w, 0.f);
  ((float4*)h1)[id] = v;
}

// histogram of dst over the E real edges (count pre-zeroed by Wfuse GEMM's ZC)
__global__ __launch_bounds__(256) void hist_kernel(
    const int* __restrict__ dst_arr, int* __restrict__ count) {
  const int id = blockIdx.x * 256 + threadIdx.x;
  if (id < N_EDGES) atomicAdd(&count[dst_arr[id]], 1);
}

// Work-efficient single-block scan; +1 per node folds in the self-loop.
__global__ __launch_bounds__(256) void scan_kernel(
    const int* __restrict__ count, int* __restrict__ offsets,
    int* __restrict__ cursor, int n) {
  constexpr int PER = 40;  // 256*40 = 10240 >= 10000
  __shared__ int sums[256];
  const int t = threadIdx.x;
  const int base = t * PER;
  int loc[PER];
  int s = 0;
#pragma unroll
  for (int k = 0; k < PER; ++k) {
    const int i = base + k;
    const int v = (i < n) ? count[i] + 1 : 0;   // +1 = self-loop
    loc[k] = s;
    s += v;
  }
  sums[t] = s;
  __syncthreads();
#pragma unroll
  for (int off = 1; off < 256; off <<= 1) {
    const int add = (t >= off) ? sums[t - off] : 0;
    __syncthreads();
    sums[t] += add;
    __syncthreads();
  }
  const int carry = (t == 0) ? 0 : sums[t - 1];
#pragma unroll
  for (int k = 0; k < PER; ++k) {
    const int i = base + k;
    if (i < n) {
      const int o = carry + loc[k];
      offsets[i] = o;
      cursor[i]  = o;
    }
  }
  if (t == 255) offsets[n] = sums[255];
}

__global__ __launch_bounds__(256) void scatter_kernel(
    const int* __restrict__ src_arr, const int* __restrict__ dst_arr,
    int* __restrict__ cursor, int* __restrict__ src_sorted) {
  const int id = blockIdx.x * 256 + threadIdx.x;
  int s, d;
  if (id < N_EDGES)                { s = src_arr[id]; d = dst_arr[id]; }
  else if (id < N_EDGES + N_NODES) { s = d = id - N_EDGES; }
  else return;
  const int pos = atomicAdd(&cursor[d], 1);
  src_sorted[pos] = s;
}

// ---------------------------------------------------------------------------
// One block (256 thr) per destination node, g in bf16.
// Thread t = (edge-slot gg=t>>6, channel-quad sub=t&63): ushort4 gather
// (8 B/lane, 512 B contiguous per wave per edge), 4 fma/iter, 4 edges in
// flight -> 4x fewer loop iterations than the 1-channel/lane R5 version.
// Cross-group (4-way) LDS reduce at the end. alpha = exp(leaky(e))/sum
// (max-shift removable: |e| bounded, fp32-safe).
// ---------------------------------------------------------------------------
__global__ __launch_bounds__(256) void aggregate_kernel(
    const unsigned short* __restrict__ g, const float* __restrict__ a_src,
    const float* __restrict__ a_dst, const int* __restrict__ offsets,
    const int* __restrict__ src_sorted, const float* __restrict__ bias_g,
    float* __restrict__ out) {
  const int i = blockIdx.x;
  const int t = threadIdx.x;
  const int start = offsets[i], end = offsets[i + 1];
  const int gg  = t >> 6;      // edge slot 0..3
  const int sub = t & 63;      // channel-quad index (chans sub*4 .. sub*4+3)
  const int h   = sub >> 4;    // head of those channels
  __shared__ float f_adst[4];
  __shared__ int   sidx_buf[256];
  __shared__ float w_buf[256 * 4];
  __shared__ float accs[4][64][4];
  __shared__ float ss[4][4];
  if (t < 4) f_adst[t] = a_dst[i * 4 + t];
  __syncthreads();
  const int   hh      = t & 3;
  const float adst_hh = f_adst[hh];

  float a0 = 0.f, a1 = 0.f, a2 = 0.f, a3 = 0.f, s_loc = 0.f;
  for (int cbase = start; cbase < end; cbase += 256) {
    const int cnt = min(256, end - cbase);
    if (t < cnt) sidx_buf[t] = src_sorted[cbase + t];
    __syncthreads();
    for (int jj = t >> 2; jj < cnt; jj += 64) {
      float e = a_src[sidx_buf[jj] * 4 + hh] + adst_hh;
      e = (e > 0.f) ? e : NEG_SLOPE * e;
      w_buf[jj * 4 + hh] = __expf(e);
    }
    __syncthreads();
#pragma unroll 4
    for (int j4 = gg; j4 < cnt; j4 += 4) {
      const float w    = w_buf[j4 * 4 + h];
      const int   sidx = sidx_buf[j4];
      const ushort4 gv = *(const ushort4*)(g + (size_t)sidx * HC + sub * 4);
      s_loc += w;
      a0 = fmaf(w, bf2f(gv.x), a0);
      a1 = fmaf(w, bf2f(gv.y), a1);
      a2 = fmaf(w, bf2f(gv.z), a2);
      a3 = fmaf(w, bf2f(gv.w), a3);
    }
    __syncthreads();
  }
  accs[gg][sub][0] = a0; accs[gg][sub][1] = a1;
  accs[gg][sub][2] = a2; accs[gg][sub][3] = a3;
  if ((sub & 15) == 0) ss[gg][h] = s_loc;   // 16 threads/head hold same s_loc
  __syncthreads();
  const int cs = t >> 2, cj = t & 3, ch = t >> 6;  // channel c = t
  const float tot = accs[0][cs][cj] + accs[1][cs][cj]
                  + accs[2][cs][cj] + accs[3][cs][cj];
  const float s = ss[0][ch] + ss[1][ch] + ss[2][ch] + ss[3][ch];
  out[(size_t)i * HC + t] = tot / s + bias_g[t];
}

// ---------------------------------------------------------------------------
extern "C" void kernel_launch(void* const* d_in, const int* in_sizes, int n_in,
                              void* d_out, int out_size, void* d_ws, size_t ws_size,
                              hipStream_t stream) {
  const float* x       = (const float*)d_in[0];
  const int*   ei      = (const int*)d_in[1];   // [2,E] int32: src then dst
  const float* W1      = (const float*)d_in[2];
  const float* b1      = (const float*)d_in[3];
  const float* W2      = (const float*)d_in[4];
  const float* b2      = (const float*)d_in[5];
  const float* Wg      = (const float*)d_in[6];
  const float* att_src = (const float*)d_in[7];
  const float* att_dst = (const float*)d_in[8];
  const float* bias_g  = (const float*)d_in[9];
  float* out = (float*)d_out;

  char* ws = (char*)d_ws;
  float* h1      = (float*)ws; ws += (size_t)N_NODES * DIM_HID * 4;
  float* h1p     = (float*)ws; ws += (size_t)4 * N_NODES * DIM_HID * 4;  // split-K partials
  unsigned short* g = (unsigned short*)ws; ws += (size_t)N_NODES * HC * 2;
  float* Wfuse   = (float*)ws; ws += (size_t)(DIM_HID + 1) * HC * 4;  // +1 row = bfuse
  float* bfuse   = Wfuse + (size_t)DIM_HID * HC;
  float* a_src   = (float*)ws; ws += (size_t)N_NODES * 4 * 4;
  float* a_dst   = (float*)ws; ws += (size_t)N_NODES * 4 * 4;
  int* count     = (int*)ws;   ws += (size_t)N_NODES * 4;
  int* offsets   = (int*)ws;   ws += (size_t)(N_NODES + 4) * 4;
  int* cursor    = (int*)ws;   ws += (size_t)N_NODES * 4;
  int* src_sorted= (int*)ws;   ws += (size_t)(N_EDGES + N_NODES) * 4;

  const dim3 blk(256);
  // [Wfuse; bfuse] = [W2; b2] @ Wg  (M=129, XB row from b2) + count zeroing
  gemm_kernel<false, false, false, false, false, true, true>
      <<<dim3(3, 4), blk, 0, stream>>>(
      W2, Wg, nullptr, Wfuse, DIM_HID + 1, HC, DIM_HID, DIM_HID,
      nullptr, nullptr, nullptr, nullptr, b2, count);
  // encoder layer 1, split-K=4: 157*2*4 = 1256 blocks
  gemm_kernel<false, false, false, true, false, false, false>
      <<<dim3(157, 2, 4), blk, 0, stream>>>(
      x, W1, nullptr, h1p, N_NODES, DIM_HID, DIM_IN, DIM_IN / 4,
      nullptr, nullptr, nullptr, nullptr, nullptr, nullptr);
  reduce_relu_bias_kernel<<<(N_NODES * DIM_HID / 4 + 255) / 256, blk, 0, stream>>>(
      h1p, b1, h1);
  // fused encoder layer 2 + GAT linear -> bf16 g, with attention epilogue
  gemm_kernel<false, true, true, false, true, false, false>
      <<<dim3(157, 4), blk, 0, stream>>>(
      h1, Wfuse, bfuse, g, N_NODES, HC, DIM_HID, DIM_HID,
      att_src, att_dst, a_src, a_dst, nullptr, nullptr);
  // CSR build (E edges + N self loops), bucketed by destination
  hist_kernel<<<(N_EDGES + 255) / 256, blk, 0, stream>>>(ei + N_EDGES, count);
  scan_kernel<<<1, 256, 0, stream>>>(count, offsets, cursor, N_NODES);
  const int nEdgeBlk = (N_EDGES + N_NODES + 255) / 256;
  scatter_kernel<<<nEdgeBlk, blk, 0, stream>>>(ei, ei + N_EDGES, cursor, src_sorted);
  // segment softmax + weighted aggregate, one block per node
  aggregate_kernel<<<N_NODES, blk, 0, stream>>>(g, a_src, a_dst, offsets, src_sorted, bias_g, out);
}

// Round 8
// 191.214 us; speedup vs baseline: 1.5346x; 1.1410x over previous
//
#include <hip/hip_runtime.h>

#define N_NODES 10000
#define N_EDGES 320000
#define DIM_IN  512
#define DIM_HID 128
#define HC      256   // HEADS*GC
#define NEG_SLOPE 0.2f

typedef short short8 __attribute__((ext_vector_type(8)));
typedef float floatx4 __attribute__((ext_vector_type(4)));

__device__ __forceinline__ unsigned short f2bf(float x) {  // RNE fp32->bf16
  unsigned int u = __float_as_uint(x);
  u += 0x7FFFu + ((u >> 16) & 1u);
  return (unsigned short)(u >> 16);
}
__device__ __forceinline__ float bf2f(unsigned short s) {
  return __uint_as_float(((unsigned int)s) << 16);
}

// ---------------------------------------------------------------------------
// fp32 vector GEMM — now only for the tiny [W2;b2]@Wg pre-fusion (12 blocks).
// XB: virtual extra A row (M-1) read from xrow (b2). ZC: zeroes count buffer.
// ---------------------------------------------------------------------------
__global__ __launch_bounds__(256) void gemm0_kernel(
    const float* __restrict__ A, const float* __restrict__ B,
    float* __restrict__ C, int M, int N, int K,
    const float* __restrict__ xrow, int* __restrict__ zero_buf) {
  constexpr int BM = 64, BN = 64, BK = 16;
  __shared__ float Ast[BK][BM + 4];
  __shared__ float Bs[BK][BN];
  const int t  = threadIdx.x;
  {
    const int flat = (blockIdx.x * gridDim.y + blockIdx.y) * 256 + t;
    if (flat < (N_NODES + 3) / 4) ((int4*)zero_buf)[flat] = make_int4(0, 0, 0, 0);
  }
  const int tx = t & 15, ty = t >> 4;
  const int m0 = blockIdx.x * BM, n0 = blockIdx.y * BN;
  const int ar = t >> 2, ac4 = (t & 3) * 4;
  const int br = t >> 4, bc4 = (t & 15) * 4;
  const int arow = m0 + ar;
  float acc[4][4] = {};
  float4 av, bv, avn, bvn;
  auto gload = [&](int k0, float4& a4, float4& b4) {
    if (arow < M - 1)       a4 = *(const float4*)(A + (size_t)arow * K + k0 + ac4);
    else if (arow == M - 1) a4 = *(const float4*)(xrow + k0 + ac4);
    else                    a4 = make_float4(0.f, 0.f, 0.f, 0.f);
    b4 = *(const float4*)(B + (size_t)(k0 + br) * N + n0 + bc4);
  };
  gload(0, av, bv);
  for (int k0 = 0; k0 < K; k0 += BK) {
    Ast[ac4 + 0][ar] = av.x; Ast[ac4 + 1][ar] = av.y;
    Ast[ac4 + 2][ar] = av.z; Ast[ac4 + 3][ar] = av.w;
    *(float4*)&Bs[br][bc4] = bv;
    __syncthreads();
    if (k0 + BK < K) gload(k0 + BK, avn, bvn);
#pragma unroll
    for (int kk = 0; kk < BK; ++kk) {
      const float4 a = *(const float4*)&Ast[kk][ty * 4];
      const float4 b = *(const float4*)&Bs[kk][tx * 4];
      const float as[4] = {a.x, a.y, a.z, a.w};
      const float bs[4] = {b.x, b.y, b.z, b.w};
#pragma unroll
      for (int i = 0; i < 4; ++i)
#pragma unroll
        for (int j = 0; j < 4; ++j) acc[i][j] = fmaf(as[i], bs[j], acc[i][j]);
    }
    __syncthreads();
    av = avn; bv = bvn;
  }
#pragma unroll
  for (int i = 0; i < 4; ++i) {
    const int row = m0 + ty * 4 + i;
    if (row < M)
      *(float4*)(C + (size_t)row * N + n0 + tx * 4) =
          make_float4(acc[i][0], acc[i][1], acc[i][2], acc[i][3]);
  }
}

// ---------------------------------------------------------------------------
// Transpose+convert weights to bf16 [N][K] for MFMA B-staging.
// blocks 0..63: W1 [512][128] -> W1T [128][512]; 64..95: Wf [128][256] -> WfT.
// ---------------------------------------------------------------------------
__global__ __launch_bounds__(256) void transpose_bf16_kernel(
    const float* __restrict__ W1, unsigned short* __restrict__ W1T,
    const float* __restrict__ Wf, unsigned short* __restrict__ WfT) {
  __shared__ unsigned short td[32][33];
  int b = blockIdx.x;
  const float* src; unsigned short* dst; int R, r0, c0;
  if (b < 64) { src = W1; dst = W1T; R = 512; r0 = (b >> 2) * 32; c0 = (b & 3) * 32; }
  else { b -= 64; src = Wf; dst = WfT; R = 128; r0 = (b >> 3) * 32; c0 = (b & 7) * 32; }
  const int C = (src == W1) ? 128 : 256;
  const int tx = threadIdx.x & 31, ty = threadIdx.x >> 5;
#pragma unroll
  for (int p = 0; p < 4; ++p)
    td[tx][ty + p * 8] = f2bf(src[(size_t)(r0 + ty + p * 8) * C + c0 + tx]);
  __syncthreads();
#pragma unroll
  for (int p = 0; p < 4; ++p)
    dst[(size_t)(c0 + ty + p * 8) * R + r0 + tx] = td[ty + p * 8][tx];
}

// ---------------------------------------------------------------------------
// bf16 MFMA GEMM: C[M,N] = A[M,K] @ B[K,N], B given as bf16 BT[N][K].
// BM=BN=64, BK=32, 256 thr = 4 waves; wave w owns rows w*16..+15, 4 N-tiles
// of 16x16x32 MFMA. LDS rows padded to 48 ushorts (96 B) -> 16B-aligned
// conflict-free ds_read_b128 frags. Single LDS buffer + register prefetch.
// Fragment maps (guide §3, m89-verified): A[m=lane&15][k=quad*8+j],
// B[k=quad*8+j][n=lane&15], C/D col=lane&15 row=quad*4+reg.
// AF32: A is fp32, converted to bf16 during staging. SPLITK: z K-chunks.
// OUTBF16: bf16 C (+bias, +ATT attention-score epilogue, one head/block).
// HIST/SCATTER: unrelated edge work folded into the preamble (saves launches).
// ---------------------------------------------------------------------------
template<bool AF32, bool SPLITK, bool ATT, bool OUTBF16, bool HIST, bool SCATTER>
__global__ __launch_bounds__(256) void mfma_gemm_kernel(
    const void* __restrict__ Av, const unsigned short* __restrict__ BT,
    const float* __restrict__ bias, void* __restrict__ Cv,
    int M, int N, int K, int KS,
    const float* __restrict__ att_src, const float* __restrict__ att_dst,
    float* __restrict__ a_src, float* __restrict__ a_dst,
    const int* __restrict__ e_src, const int* __restrict__ e_dst,
    int* __restrict__ cnt_or_cur, int* __restrict__ src_sorted) {
  constexpr int BM = 64, BN = 64, BK = 32;
  __shared__ unsigned short As[BM][48];
  __shared__ unsigned short Bs[BN][48];
  const int t = threadIdx.x;

  if (HIST) {
    const int nthr = gridDim.x * gridDim.y * gridDim.z * 256;
    const int flat = ((blockIdx.z * gridDim.y + blockIdx.y) * gridDim.x + blockIdx.x) * 256 + t;
    for (int e = flat; e < N_EDGES; e += nthr) atomicAdd(&cnt_or_cur[e_dst[e]], 1);
  }
  if (SCATTER) {
    const int nthr = gridDim.x * gridDim.y * 256;
    const int flat = (blockIdx.y * gridDim.x + blockIdx.x) * 256 + t;
    for (int id = flat; id < N_EDGES + N_NODES; id += nthr) {
      int s, d;
      if (id < N_EDGES) { s = e_src[id]; d = e_dst[id]; }
      else              { s = d = id - N_EDGES; }
      src_sorted[atomicAdd(&cnt_or_cur[d], 1)] = s;
    }
  }

  const int m0 = blockIdx.x * BM, n0 = blockIdx.y * BN;
  const int kbase = SPLITK ? blockIdx.z * KS : 0;
  const int w = t >> 6, L = t & 63;
  const int lm = L & 15, q = L >> 4;
  floatx4 acc[4] = {};

  // staging registers
  float4 a32_0, a32_1, a32n_0, a32n_1;
  uint4  ab, abn, bb, bbn;
  auto load_stage = [&](int kb, float4& v0, float4& v1, uint4& va, uint4& vb) {
    if (AF32) {
      const float* A = (const float*)Av;
      const int r = t >> 3, c = (t & 7) * 4;
      v0 = (m0 + r < M) ? *(const float4*)(A + (size_t)(m0 + r) * K + kb + c)
                        : make_float4(0.f, 0.f, 0.f, 0.f);
      v1 = (m0 + r + 32 < M) ? *(const float4*)(A + (size_t)(m0 + r + 32) * K + kb + c)
                             : make_float4(0.f, 0.f, 0.f, 0.f);
    } else {
      const unsigned short* A = (const unsigned short*)Av;
      va = *(const uint4*)(A + (size_t)(m0 + (t >> 2)) * K + kb + (t & 3) * 8);
    }
    vb = *(const uint4*)(BT + (size_t)(n0 + (t >> 2)) * K + kb + (t & 3) * 8);
  };
  auto store_stage = [&](const float4& v0, const float4& v1, const uint4& va, const uint4& vb) {
    if (AF32) {
      const int r = t >> 3, c = (t & 7) * 4;
      ushort4 s0 = {f2bf(v0.x), f2bf(v0.y), f2bf(v0.z), f2bf(v0.w)};
      ushort4 s1 = {f2bf(v1.x), f2bf(v1.y), f2bf(v1.z), f2bf(v1.w)};
      *(ushort4*)&As[r][c]      = s0;
      *(ushort4*)&As[r + 32][c] = s1;
    } else {
      *(uint4*)&As[t >> 2][(t & 3) * 8] = va;
    }
    *(uint4*)&Bs[t >> 2][(t & 3) * 8] = vb;
  };

  const int NT = KS / BK;
  load_stage(kbase, a32_0, a32_1, ab, bb);
  for (int kt = 0; kt < NT; ++kt) {
    store_stage(a32_0, a32_1, ab, bb);
    __syncthreads();
    if (kt + 1 < NT) load_stage(kbase + (kt + 1) * BK, a32n_0, a32n_1, abn, bbn);
    const short8 af = *(const short8*)&As[w * 16 + lm][q * 8];
#pragma unroll
    for (int nt = 0; nt < 4; ++nt) {
      const short8 bf = *(const short8*)&Bs[nt * 16 + lm][q * 8];
      acc[nt] = __builtin_amdgcn_mfma_f32_16x16x32_bf16(af, bf, acc[nt], 0, 0, 0);
    }
    __syncthreads();
    a32_0 = a32n_0; a32_1 = a32n_1; ab = abn; bb = bbn;
  }

  const int row0 = m0 + w * 16 + q * 4;
  if (SPLITK) {
    float* Cb = (float*)Cv + (size_t)blockIdx.z * M * N;
#pragma unroll
    for (int nt = 0; nt < 4; ++nt) {
      const int col = n0 + nt * 16 + lm;
#pragma unroll
      for (int r = 0; r < 4; ++r)
        if (row0 + r < M) Cb[(size_t)(row0 + r) * N + col] = acc[nt][r];
    }
  }
  if (OUTBF16) {
    unsigned short* G = (unsigned short*)Cv;
    const int hh = n0 >> 6;
    float ps[4] = {}, pd[4] = {};
#pragma unroll
    for (int nt = 0; nt < 4; ++nt) {
      const int col = n0 + nt * 16 + lm;
      const float bv = bias ? bias[col] : 0.f;
      const float as_c = ATT ? att_src[hh * 64 + nt * 16 + lm] : 0.f;
      const float ad_c = ATT ? att_dst[hh * 64 + nt * 16 + lm] : 0.f;
#pragma unroll
      for (int r = 0; r < 4; ++r) {
        const float gv = acc[nt][r] + bv;
        if (row0 + r < M) G[(size_t)(row0 + r) * N + col] = f2bf(gv);
        if (ATT) { ps[r] = fmaf(gv, as_c, ps[r]); pd[r] = fmaf(gv, ad_c, pd[r]); }
      }
    }
    if (ATT) {
#pragma unroll
      for (int r = 0; r < 4; ++r) {
#pragma unroll
        for (int off = 1; off < 16; off <<= 1) {
          ps[r] += __shfl_xor(ps[r], off);
          pd[r] += __shfl_xor(pd[r], off);
        }
        if (lm == 0 && row0 + r < M) {
          a_src[(row0 + r) * 4 + hh] = ps[r];
          a_dst[(row0 + r) * 4 + hh] = pd[r];
        }
      }
    }
  }
}

// h1b = bf16(relu(sum_z part[z] + b1))
__global__ __launch_bounds__(256) void reduce_relu_bias_kernel(
    const float* __restrict__ part, const float* __restrict__ b1,
    unsigned short* __restrict__ h1b) {
  const int id = blockIdx.x * 256 + threadIdx.x;   // float4 index
  constexpr int TOT = N_NODES * DIM_HID / 4;
  if (id >= TOT) return;
  const float4* p = (const float4*)part;
  float4 v = p[id];
#pragma unroll
  for (int s = 1; s < 4; ++s) {
    const float4 w = p[id + (size_t)s * TOT];
    v.x += w.x; v.y += w.y; v.z += w.z; v.w += w.w;
  }
  const float4 bv = *(const float4*)(b1 + (id & 31) * 4);
  ushort4 o;
  o.x = f2bf(fmaxf(v.x + bv.x, 0.f)); o.y = f2bf(fmaxf(v.y + bv.y, 0.f));
  o.z = f2bf(fmaxf(v.z + bv.z, 0.f)); o.w = f2bf(fmaxf(v.w + bv.w, 0.f));
  *(ushort4*)(h1b + (size_t)id * 4) = o;
}

// Work-efficient single-block scan; +1 per node folds in the self-loop.
__global__ __launch_bounds__(256) void scan_kernel(
    const int* __restrict__ count, int* __restrict__ offsets,
    int* __restrict__ cursor, int n) {
  constexpr int PER = 40;
  __shared__ int sums[256];
  const int t = threadIdx.x;
  const int base = t * PER;
  int loc[PER];
  int s = 0;
#pragma unroll
  for (int k = 0; k < PER; ++k) {
    const int i = base + k;
    const int v = (i < n) ? count[i] + 1 : 0;   // +1 = self-loop
    loc[k] = s;
    s += v;
  }
  sums[t] = s;
  __syncthreads();
#pragma unroll
  for (int off = 1; off < 256; off <<= 1) {
    const int add = (t >= off) ? sums[t - off] : 0;
    __syncthreads();
    sums[t] += add;
    __syncthreads();
  }
  const int carry = (t == 0) ? 0 : sums[t - 1];
#pragma unroll
  for (int k = 0; k < PER; ++k) {
    const int i = base + k;
    if (i < n) {
      const int o = carry + loc[k];
      offsets[i] = o;
      cursor[i]  = o;
    }
  }
  if (t == 255) offsets[n] = sums[255];
}

// ---------------------------------------------------------------------------
// One block per destination node, g in bf16; t = (edge-slot t>>6, chan-quad
// t&63); ushort4 gathers, 4 edges in flight, 4-way LDS reduce at the end.
// alpha = exp(leaky(e))/sum (max-shift removable: |e| bounded, fp32-safe).
// ---------------------------------------------------------------------------
__global__ __launch_bounds__(256) void aggregate_kernel(
    const unsigned short* __restrict__ g, const float* __restrict__ a_src,
    const float* __restrict__ a_dst, const int* __restrict__ offsets,
    const int* __restrict__ src_sorted, const float* __restrict__ bias_g,
    float* __restrict__ out) {
  const int i = blockIdx.x;
  const int t = threadIdx.x;
  const int start = offsets[i], end = offsets[i + 1];
  const int gg  = t >> 6;
  const int sub = t & 63;
  const int h   = sub >> 4;
  __shared__ float f_adst[4];
  __shared__ int   sidx_buf[256];
  __shared__ float w_buf[256 * 4];
  __shared__ float accs[4][64][4];
  __shared__ float ss[4][4];
  if (t < 4) f_adst[t] = a_dst[i * 4 + t];
  __syncthreads();
  const int   hh      = t & 3;
  const float adst_hh = f_adst[hh];

  float a0 = 0.f, a1 = 0.f, a2 = 0.f, a3 = 0.f, s_loc = 0.f;
  for (int cbase = start; cbase < end; cbase += 256) {
    const int cnt = min(256, end - cbase);
    if (t < cnt) sidx_buf[t] = src_sorted[cbase + t];
    __syncthreads();
    for (int jj = t >> 2; jj < cnt; jj += 64) {
      float e = a_src[sidx_buf[jj] * 4 + hh] + adst_hh;
      e = (e > 0.f) ? e : NEG_SLOPE * e;
      w_buf[jj * 4 + hh] = __expf(e);
    }
    __syncthreads();
#pragma unroll 4
    for (int j4 = gg; j4 < cnt; j4 += 4) {
      const float w    = w_buf[j4 * 4 + h];
      const int   sidx = sidx_buf[j4];
      const ushort4 gv = *(const ushort4*)(g + (size_t)sidx * HC + sub * 4);
      s_loc += w;
      a0 = fmaf(w, bf2f(gv.x), a0);
      a1 = fmaf(w, bf2f(gv.y), a1);
      a2 = fmaf(w, bf2f(gv.z), a2);
      a3 = fmaf(w, bf2f(gv.w), a3);
    }
    __syncthreads();
  }
  accs[gg][sub][0] = a0; accs[gg][sub][1] = a1;
  accs[gg][sub][2] = a2; accs[gg][sub][3] = a3;
  if ((sub & 15) == 0) ss[gg][h] = s_loc;
  __syncthreads();
  const int cs = t >> 2, cj = t & 3, ch = t >> 6;
  const float tot = accs[0][cs][cj] + accs[1][cs][cj]
                  + accs[2][cs][cj] + accs[3][cs][cj];
  const float s = ss[0][ch] + ss[1][ch] + ss[2][ch] + ss[3][ch];
  out[(size_t)i * HC + t] = tot / s + bias_g[t];
}

// ---------------------------------------------------------------------------
extern "C" void kernel_launch(void* const* d_in, const int* in_sizes, int n_in,
                              void* d_out, int out_size, void* d_ws, size_t ws_size,
                              hipStream_t stream) {
  const float* x       = (const float*)d_in[0];
  const int*   ei      = (const int*)d_in[1];   // [2,E] int32: src then dst
  const float* W1      = (const float*)d_in[2];
  const float* b1      = (const float*)d_in[3];
  const float* W2      = (const float*)d_in[4];
  const float* b2      = (const float*)d_in[5];
  const float* Wg      = (const float*)d_in[6];
  const float* att_src = (const float*)d_in[7];
  const float* att_dst = (const float*)d_in[8];
  const float* bias_g  = (const float*)d_in[9];
  float* out = (float*)d_out;

  char* ws = (char*)d_ws;
  unsigned short* h1b = (unsigned short*)ws; ws += (size_t)(N_NODES + 64) * DIM_HID * 2;
  float* h1p     = (float*)ws; ws += (size_t)4 * N_NODES * DIM_HID * 4;
  unsigned short* g = (unsigned short*)ws; ws += (size_t)N_NODES * HC * 2;
  float* Wfuse   = (float*)ws; ws += (size_t)(DIM_HID + 1) * HC * 4;
  float* bfuse   = Wfuse + (size_t)DIM_HID * HC;
  unsigned short* W1T = (unsigned short*)ws; ws += (size_t)DIM_HID * DIM_IN * 2;
  unsigned short* WfT = (unsigned short*)ws; ws += (size_t)HC * DIM_HID * 2;
  float* a_src   = (float*)ws; ws += (size_t)N_NODES * 4 * 4;
  float* a_dst   = (float*)ws; ws += (size_t)N_NODES * 4 * 4;
  int* count     = (int*)ws;   ws += (size_t)N_NODES * 4;
  int* offsets   = (int*)ws;   ws += (size_t)(N_NODES + 4) * 4;
  int* cursor    = (int*)ws;   ws += (size_t)N_NODES * 4;
  int* src_sorted= (int*)ws;   ws += (size_t)(N_EDGES + N_NODES) * 4;

  const dim3 blk(256);
  // 1. [Wfuse; bfuse] = [W2; b2] @ Wg  + count zeroing
  gemm0_kernel<<<dim3(3, 4), blk, 0, stream>>>(
      W2, Wg, Wfuse, DIM_HID + 1, HC, DIM_HID, b2, count);
  // 2. W1 -> W1T bf16 [128][512]; Wfuse -> WfT bf16 [256][128]
  transpose_bf16_kernel<<<96, blk, 0, stream>>>(W1, W1T, Wfuse, WfT);
  // 3. encoder layer 1 MFMA, split-K=4 (1256 blocks) + edge histogram
  mfma_gemm_kernel<true, true, false, false, true, false>
      <<<dim3(157, 2, 4), blk, 0, stream>>>(
      x, W1T, nullptr, h1p, N_NODES, DIM_HID, DIM_IN, DIM_IN / 4,
      nullptr, nullptr, nullptr, nullptr, nullptr, ei + N_EDGES, count, nullptr);
  // 4. h1b = bf16(relu(sum partials + b1))
  reduce_relu_bias_kernel<<<(N_NODES * DIM_HID / 4 + 255) / 256, blk, 0, stream>>>(
      h1p, b1, h1b);
  // 5. CSR offsets (+1 self-loop per node)
  scan_kernel<<<1, 256, 0, stream>>>(count, offsets, cursor, N_NODES);
  // 6. fused layer2+GAT MFMA -> bf16 g, attention epilogue, + edge scatter
  mfma_gemm_kernel<false, false, true, true, false, true>
      <<<dim3(157, 4), blk, 0, stream>>>(
      h1b, WfT, bfuse, g, N_NODES, HC, DIM_HID, DIM_HID,
      att_src, att_dst, a_src, a_dst, ei, ei + N_EDGES, cursor, src_sorted);
  // 7. segment softmax + weighted aggregate
  aggregate_kernel<<<N_NODES, blk, 0, stream>>>(
      g, a_src, a_dst, offsets, src_sorted, bias_g, out);
}